// Round 5
// baseline (68.882 us; speedup 1.0000x reference)
//
#include <hip/hip_runtime.h>
#include <hip/hip_bf16.h>

typedef short  short8 __attribute__((ext_vector_type(8)));
typedef float  f32x4  __attribute__((ext_vector_type(4)));
typedef unsigned int u32;
typedef unsigned long long u64;
typedef unsigned short u16;

// ---------- helpers ----------
__device__ __forceinline__ u32 f2bf(float v) {              // fp32 -> bf16 bits (RNE), prep only
    u32 u = __float_as_uint(v);
    return (u + 0x7FFFu + ((u >> 16) & 1u)) >> 16;
}
__device__ __forceinline__ float qround128(float w) {       // round(w*128) clip [-128,127]
    float q = rintf(w * 128.0f);
    return fminf(fmaxf(q, -128.0f), 127.0f);
}
// packed RNE f32x2 -> bf16x2 (v_cvt_pk_bf16_f32)
__device__ __forceinline__ u32 cvtpk(float a, float b) {
    __hip_bfloat162 h = __float22bfloat162_rn(make_float2(a, b));
    union { __hip_bfloat162 h; u32 u; } cv; cv.h = h; return cv.u;
}
// qrelu in integer domain: k = clamp(rndne(acc),0,255); k exact in bf16.
__device__ __forceinline__ u64 qrelu_pack4(f32x4 a) {
    float q0 = fminf(fmaxf(rintf(a[0]), 0.f), 255.f);
    float q1 = fminf(fmaxf(rintf(a[1]), 0.f), 255.f);
    float q2 = fminf(fmaxf(rintf(a[2]), 0.f), 255.f);
    float q3 = fminf(fmaxf(rintf(a[3]), 0.f), 255.f);
    return (u64)cvtpk(q0, q1) | ((u64)cvtpk(q2, q3) << 32);
}
union FragU { short8 s; u32 u[4]; };
__device__ __forceinline__ f32x4 mfma16(short8 a, short8 b, f32x4 c) {
    return __builtin_amdgcn_mfma_f32_16x16x32_bf16(a, b, c, 0, 0, 0);
}

// ---------- ws layout (unchanged from round 3, verified) ----------
__global__ void prep(const float* __restrict__ w1, const float* __restrict__ b1,
                     const float* __restrict__ w2, const float* __restrict__ b2,
                     const float* __restrict__ w3, const float* __restrict__ b3,
                     const float* __restrict__ wo, const float* __restrict__ bo,
                     u16* __restrict__ wsh) {
    int t = threadIdx.x;
    for (int idx = t; idx < 16 * 512; idx += 256) {
        int blk = idx >> 9, e = idx & 511;
        int l = e >> 3, j = e & 7;
        int r  = l & 15;
        int kk = ((l >> 4) << 3) + j;
        float val = 0.f;
        if (blk < 8) {
            int mt = blk >> 1, ks = blk & 1;
            int k = ks * 32 + kk, fo = mt * 16 + r;
            if (k < 48) val = 2.0f * qround128(w1[k * 64 + fo]);
        } else if (blk < 12) {
            int bi = blk - 8, mt = bi >> 1, ks = bi & 1;
            int k = ks * 32 + kk, fo = mt * 16 + r;
            val = qround128(w2[k * 32 + fo]) * (1.0f / 128.0f);
        } else if (blk < 14) {
            int mt = blk - 12;
            val = qround128(w3[kk * 32 + mt * 16 + r]) * (1.0f / 128.0f);
        } else {
            float wv = (r < 5) ? wo[kk * 5 + r] * (1.0f / 256.0f) : 0.f;
            u32 hb = f2bf(wv);
            if (blk == 14) { wsh[idx] = (u16)hb; continue; }
            val = wv - __uint_as_float(hb << 16);
        }
        wsh[idx] = (u16)f2bf(val);
    }
    float* wsf = (float*)(wsh + 8192);
    for (int i = t; i < 64; i += 256) wsf[i]       = 2.0f * qround128(b1[i]);
    for (int i = t; i < 32; i += 256) wsf[64 + i]  = 2.0f * qround128(b2[i]);
    for (int i = t; i < 32; i += 256) wsf[96 + i]  = 2.0f * qround128(b3[i]);
    for (int i = t; i < 16; i += 256) wsf[128 + i] = (i < 5) ? bo[i] : 0.f;
}

// ---------- main kernel ----------
// Transposed dataflow (round-3 verified): D = A*B, A = W^T resident in VGPRs,
// B = H^T. 2 TILES PER WAVE PER ITERATION: two independent dependency chains
// interleave, hiding the LDS-round-trip + MFMA latency that capped round 3/4.
// LDS row stride 88 shorts (176B): 16B-aligned b128, max 2-way bank aliasing.

#define RS 88           // LDS row stride in shorts
#define SLAB 4224       // per-tile slab: 3 * 16 * RS

__global__ __launch_bounds__(256, 2) void mlp_mfma(const float* __restrict__ x,
                                                   const u16* __restrict__ wsh,
                                                   float* __restrict__ out, int ntiles) {
    __shared__ __align__(16) u16 smem[4][2][SLAB];
    const int tid = threadIdx.x;
    const int wid = tid >> 6, lane = tid & 63;
    const int c = lane & 15, g = lane >> 4;

    // resident weight A-fragments (64 VGPR)
    short8 wf[16];
    const short8* wv = (const short8*)wsh;
    #pragma unroll
    for (int i = 0; i < 16; ++i) wf[i] = wv[i * 64 + lane];

    // biases: acc reg r <-> out-feat mt*16 + 4g + r
    const float* wsf = (const float*)(wsh + 8192);
    f32x4 b1q[4], b2q[2], b3q[2], boq;
    #pragma unroll
    for (int i = 0; i < 4; ++i) b1q[i] = *(const f32x4*)(wsf + i * 16 + 4 * g);
    #pragma unroll
    for (int i = 0; i < 2; ++i) b2q[i] = *(const f32x4*)(wsf + 64 + i * 16 + 4 * g);
    #pragma unroll
    for (int i = 0; i < 2; ++i) b3q[i] = *(const f32x4*)(wsf + 96 + i * 16 + 4 * g);
    boq = *(const f32x4*)(wsf + 128 + 4 * g);

    const int xoff = c * 48 + g * 8;
    const int npairs = (ntiles + 1) >> 1;
    const int gw = blockIdx.x * 4 + wid;
    const int nw = gridDim.x * 4;

    for (int p = gw; p < npairs; p += nw) {
        int tt[2];
        tt[0] = 2 * p;
        tt[1] = (2 * p + 1 < ntiles) ? (2 * p + 1) : (2 * p);

        // ---- load both tiles' x (independent, issue together)
        float4 xa[2], xb[2], xc[2], xd[2];
        #pragma unroll
        for (int u = 0; u < 2; ++u) {
            const float* xl = x + (size_t)tt[u] * 768 + xoff;
            xa[u] = *(const float4*)(xl);
            xb[u] = *(const float4*)(xl + 4);
            xc[u] = make_float4(0.f, 0.f, 0.f, 0.f);
            xd[u] = make_float4(0.f, 0.f, 0.f, 0.f);
            if (g < 2) { xc[u] = *(const float4*)(xl + 32); xd[u] = *(const float4*)(xl + 36); }
        }

        // ---- hi/lo bf16 split (both tiles)
        FragU bh0[2], bl0[2], bh1[2], bl1[2];
        #pragma unroll
        for (int u = 0; u < 2; ++u) {
            float v0[8] = {xa[u].x, xa[u].y, xa[u].z, xa[u].w, xb[u].x, xb[u].y, xb[u].z, xb[u].w};
            float v1[8] = {xc[u].x, xc[u].y, xc[u].z, xc[u].w, xd[u].x, xd[u].y, xd[u].z, xd[u].w};
            #pragma unroll
            for (int q = 0; q < 4; ++q) {
                u32 uu = cvtpk(v0[2 * q], v0[2 * q + 1]);
                bh0[u].u[q] = uu;
                float r0 = v0[2 * q]     - __uint_as_float(uu << 16);
                float r1 = v0[2 * q + 1] - __uint_as_float(uu & 0xFFFF0000u);
                bl0[u].u[q] = cvtpk(r0, r1);
                u32 ww = cvtpk(v1[2 * q], v1[2 * q + 1]);
                bh1[u].u[q] = ww;
                float s0 = v1[2 * q]     - __uint_as_float(ww << 16);
                float s1 = v1[2 * q + 1] - __uint_as_float(ww & 0xFFFF0000u);
                bl1[u].u[q] = cvtpk(s0, s1);
            }
        }

        // ---- layer 1 (both tiles): acc = 256*preact
        #pragma unroll
        for (int u = 0; u < 2; ++u) {
            u16* H = &smem[wid][u][0];
            #pragma unroll
            for (int mt = 0; mt < 4; ++mt) {
                f32x4 a = b1q[mt];
                a = mfma16(wf[mt * 2 + 0], bh0[u].s, a);
                a = mfma16(wf[mt * 2 + 1], bh1[u].s, a);
                a = mfma16(wf[mt * 2 + 0], bl0[u].s, a);
                a = mfma16(wf[mt * 2 + 1], bl1[u].s, a);
                *(u64*)(H + c * RS + mt * 16 + 4 * g) = qrelu_pack4(a);
            }
        }

        // ---- layer 2 (K=64, both tiles)
        #pragma unroll
        for (int u = 0; u < 2; ++u) {
            u16* H = &smem[wid][u][0];
            short8 p0 = *(const short8*)(H + c * RS + 8 * g);
            short8 p1 = *(const short8*)(H + c * RS + 32 + 8 * g);
            #pragma unroll
            for (int mt = 0; mt < 2; ++mt) {
                f32x4 a = b2q[mt];
                a = mfma16(wf[8 + mt * 2 + 0], p0, a);
                a = mfma16(wf[8 + mt * 2 + 1], p1, a);
                *(u64*)(H + 16 * RS + c * RS + mt * 16 + 4 * g) = qrelu_pack4(a);
            }
        }

        // ---- layer 3 (K=32, both tiles)
        #pragma unroll
        for (int u = 0; u < 2; ++u) {
            u16* H = &smem[wid][u][0];
            short8 p2 = *(const short8*)(H + 16 * RS + c * RS + 8 * g);
            #pragma unroll
            for (int mt = 0; mt < 2; ++mt) {
                f32x4 a = b3q[mt];
                a = mfma16(wf[12 + mt], p2, a);
                *(u64*)(H + 32 * RS + c * RS + mt * 16 + 4 * g) = qrelu_pack4(a);
            }
        }

        // ---- output layer (both tiles)
        #pragma unroll
        for (int u = 0; u < 2; ++u) {
            u16* H = &smem[wid][u][0];
            short8 p3 = *(const short8*)(H + 32 * RS + c * RS + 8 * g);
            f32x4 ao = boq;
            ao = mfma16(wf[14], p3, ao);
            ao = mfma16(wf[15], p3, ao);
            float* orow = out + (size_t)tt[u] * 80 + c * 5;
            if (g == 0) {
                orow[0] = ao[0]; orow[1] = ao[1]; orow[2] = ao[2]; orow[3] = ao[3];
            } else if (g == 1) {
                orow[4] = ao[0];
            }
        }
    }
}

extern "C" void kernel_launch(void* const* d_in, const int* in_sizes, int n_in,
                              void* d_out, int out_size, void* d_ws, size_t ws_size,
                              hipStream_t stream) {
    const float* x  = (const float*)d_in[0];
    const float* w1 = (const float*)d_in[1];
    const float* b1 = (const float*)d_in[2];
    const float* w2 = (const float*)d_in[3];
    const float* b2 = (const float*)d_in[4];
    const float* w3 = (const float*)d_in[5];
    const float* b3 = (const float*)d_in[6];
    const float* wo = (const float*)d_in[7];
    const float* bo = (const float*)d_in[8];
    float* out = (float*)d_out;

    int B = in_sizes[0] / 48;
    int ntiles = B / 16;                       // 1e6 -> 62500 exactly

    prep<<<1, 256, 0, stream>>>(w1, b1, w2, b2, w3, b3, wo, bo, (u16*)d_ws);

    int npairs = (ntiles + 1) / 2;
    int blocks = (npairs + 3) / 4;
    if (blocks > 2048) blocks = 2048;
    mlp_mfma<<<blocks, 256, 0, stream>>>(x, (const u16*)d_ws, out, ntiles);
}

// Round 6
// 62.701 us; speedup vs baseline: 1.0986x; 1.0986x over previous
//
#include <hip/hip_runtime.h>
#include <hip/hip_bf16.h>

typedef short  short8 __attribute__((ext_vector_type(8)));
typedef float  f32x4  __attribute__((ext_vector_type(4)));
typedef unsigned int u32;
typedef unsigned long long u64;
typedef unsigned short u16;

// ---------- helpers ----------
__device__ __forceinline__ u32 f2bf(float v) {              // fp32 -> bf16 bits (RNE), prep only
    u32 u = __float_as_uint(v);
    return (u + 0x7FFFu + ((u >> 16) & 1u)) >> 16;
}
__device__ __forceinline__ float qround128(float w) {       // round(w*128) clip [-128,127]
    float q = rintf(w * 128.0f);
    return fminf(fmaxf(q, -128.0f), 127.0f);
}
// packed RNE f32x2 -> bf16x2 (v_cvt_pk_bf16_f32)
__device__ __forceinline__ u32 cvtpk(float a, float b) {
    __hip_bfloat162 h = __float22bfloat162_rn(make_float2(a, b));
    union { __hip_bfloat162 h; u32 u; } cv; cv.h = h; return cv.u;
}
// qrelu in integer domain: k = clamp(rndne(acc),0,255); k exact in bf16.
// fmin/fmax pair folds to v_med3_f32.
__device__ __forceinline__ u64 qrelu_pack4(f32x4 a) {
    float q0 = fminf(fmaxf(rintf(a[0]), 0.f), 255.f);
    float q1 = fminf(fmaxf(rintf(a[1]), 0.f), 255.f);
    float q2 = fminf(fmaxf(rintf(a[2]), 0.f), 255.f);
    float q3 = fminf(fmaxf(rintf(a[3]), 0.f), 255.f);
    return (u64)cvtpk(q0, q1) | ((u64)cvtpk(q2, q3) << 32);
}
union FragU { short8 s; u32 u[4]; };
__device__ __forceinline__ f32x4 mfma16(short8 a, short8 b, f32x4 c) {
    return __builtin_amdgcn_mfma_f32_16x16x32_bf16(a, b, c, 0, 0, 0);
}

// ---------- ws layout (unchanged from round 3, verified) ----------
__global__ void prep(const float* __restrict__ w1, const float* __restrict__ b1,
                     const float* __restrict__ w2, const float* __restrict__ b2,
                     const float* __restrict__ w3, const float* __restrict__ b3,
                     const float* __restrict__ wo, const float* __restrict__ bo,
                     u16* __restrict__ wsh) {
    int t = threadIdx.x;
    for (int idx = t; idx < 16 * 512; idx += 256) {
        int blk = idx >> 9, e = idx & 511;
        int l = e >> 3, j = e & 7;
        int r  = l & 15;
        int kk = ((l >> 4) << 3) + j;
        float val = 0.f;
        if (blk < 8) {
            int mt = blk >> 1, ks = blk & 1;
            int k = ks * 32 + kk, fo = mt * 16 + r;
            if (k < 48) val = 2.0f * qround128(w1[k * 64 + fo]);
        } else if (blk < 12) {
            int bi = blk - 8, mt = bi >> 1, ks = bi & 1;
            int k = ks * 32 + kk, fo = mt * 16 + r;
            val = qround128(w2[k * 32 + fo]) * (1.0f / 128.0f);
        } else if (blk < 14) {
            int mt = blk - 12;
            val = qround128(w3[kk * 32 + mt * 16 + r]) * (1.0f / 128.0f);
        } else {
            float wv = (r < 5) ? wo[kk * 5 + r] * (1.0f / 256.0f) : 0.f;
            u32 hb = f2bf(wv);
            if (blk == 14) { wsh[idx] = (u16)hb; continue; }
            val = wv - __uint_as_float(hb << 16);
        }
        wsh[idx] = (u16)f2bf(val);
    }
    float* wsf = (float*)(wsh + 8192);
    for (int i = t; i < 64; i += 256) wsf[i]       = 2.0f * qround128(b1[i]);
    for (int i = t; i < 32; i += 256) wsf[64 + i]  = 2.0f * qround128(b2[i]);
    for (int i = t; i < 32; i += 256) wsf[96 + i]  = 2.0f * qround128(b3[i]);
    for (int i = t; i < 16; i += 256) wsf[128 + i] = (i < 5) ? bo[i] : 0.f;
}

// ---------- main kernel ----------
// Transposed dataflow (round-3 verified): D = A*B, A = W^T resident in VGPRs,
// B = H^T.  Round-6 changes vs R4:
//   * __launch_bounds__(256,3): 3 waves/SIMD (12/CU) for latency hiding
//     (prefetch dropped to fit the 170-VGPR cap; compiler hoists loads anyway)
//   * dependent-MFMA chains split into independent accumulators + v_add:
//     L1 depth 4->2, L2 2->1, out 2->1  (L2/L3 sums are integer-exact, order-free)

__global__ __launch_bounds__(256, 3) void mlp_mfma(const float* __restrict__ x,
                                                   const u16* __restrict__ wsh,
                                                   float* __restrict__ out, int ntiles) {
    __shared__ __align__(16) u16 smem[4][3840];
    const int tid = threadIdx.x;
    const int wid = tid >> 6, lane = tid & 63;
    const int c = lane & 15, g = lane >> 4;

    // resident weight A-fragments (64 VGPR)
    short8 wf[16];
    const short8* wv = (const short8*)wsh;
    #pragma unroll
    for (int i = 0; i < 16; ++i) wf[i] = wv[i * 64 + lane];

    // biases: acc reg r <-> out-feat mt*16 + 4g + r
    const float* wsf = (const float*)(wsh + 8192);
    f32x4 b1q[4], b2q[2], b3q[2], boq;
    #pragma unroll
    for (int i = 0; i < 4; ++i) b1q[i] = *(const f32x4*)(wsf + i * 16 + 4 * g);
    #pragma unroll
    for (int i = 0; i < 2; ++i) b2q[i] = *(const f32x4*)(wsf + 64 + i * 16 + 4 * g);
    #pragma unroll
    for (int i = 0; i < 2; ++i) b3q[i] = *(const f32x4*)(wsf + 96 + i * 16 + 4 * g);
    boq = *(const f32x4*)(wsf + 128 + 4 * g);

    u16* H = &smem[wid][0];
    const int xoff = c * 48 + g * 8;

    const int gw = blockIdx.x * 4 + wid;
    const int nw = gridDim.x * 4;

    for (int t0 = gw; t0 < ntiles; t0 += nw) {
        // ---- x tile load: lane(c,g) -> batch-row c, k = 8g..8g+7 (+32 for g<2)
        const float* xl = x + (size_t)t0 * 768 + xoff;
        float4 xa = *(const float4*)(xl);
        float4 xb = *(const float4*)(xl + 4);
        float4 xc = make_float4(0.f, 0.f, 0.f, 0.f);
        float4 xd = make_float4(0.f, 0.f, 0.f, 0.f);
        if (g < 2) { xc = *(const float4*)(xl + 32); xd = *(const float4*)(xl + 36); }

        // ---- hi/lo bf16 split (B-operand fragments)
        float v0[8] = {xa.x, xa.y, xa.z, xa.w, xb.x, xb.y, xb.z, xb.w};
        float v1[8] = {xc.x, xc.y, xc.z, xc.w, xd.x, xd.y, xd.z, xd.w};
        FragU bh0, bl0, bh1, bl1;
        #pragma unroll
        for (int p = 0; p < 4; ++p) {
            u32 uu = cvtpk(v0[2 * p], v0[2 * p + 1]);
            bh0.u[p] = uu;
            float r0 = v0[2 * p]     - __uint_as_float(uu << 16);
            float r1 = v0[2 * p + 1] - __uint_as_float(uu & 0xFFFF0000u);
            bl0.u[p] = cvtpk(r0, r1);
            u32 ww = cvtpk(v1[2 * p], v1[2 * p + 1]);
            bh1.u[p] = ww;
            float s0 = v1[2 * p]     - __uint_as_float(ww << 16);
            float s1 = v1[2 * p + 1] - __uint_as_float(ww & 0xFFFF0000u);
            bl1.u[p] = cvtpk(s0, s1);
        }

        // ---- layer 1: two independent 2-deep MFMA chains per mt, then add
        #pragma unroll
        for (int mt = 0; mt < 4; ++mt) {
            f32x4 ah = b1q[mt];
            ah = mfma16(wf[mt * 2 + 0], bh0.s, ah);
            ah = mfma16(wf[mt * 2 + 1], bh1.s, ah);
            f32x4 al = {0.f, 0.f, 0.f, 0.f};
            al = mfma16(wf[mt * 2 + 0], bl0.s, al);
            al = mfma16(wf[mt * 2 + 1], bl1.s, al);
            f32x4 a = ah + al;
            *(u64*)(H + c * 80 + mt * 16 + 4 * g) = qrelu_pack4(a);
        }

        // ---- layer 2 (K=64): two independent 1-deep chains per mt
        short8 p0 = *(const short8*)(H + c * 80 + 8 * g);
        short8 p1 = *(const short8*)(H + c * 80 + 32 + 8 * g);
        #pragma unroll
        for (int mt = 0; mt < 2; ++mt) {
            f32x4 a0 = b2q[mt];
            a0 = mfma16(wf[8 + mt * 2 + 0], p0, a0);
            f32x4 a1 = {0.f, 0.f, 0.f, 0.f};
            a1 = mfma16(wf[8 + mt * 2 + 1], p1, a1);
            f32x4 a = a0 + a1;
            *(u64*)(H + 1280 + c * 80 + mt * 16 + 4 * g) = qrelu_pack4(a);
        }

        // ---- layer 3 (K=32): already depth-1
        short8 p2 = *(const short8*)(H + 1280 + c * 80 + 8 * g);
        #pragma unroll
        for (int mt = 0; mt < 2; ++mt) {
            f32x4 a = b3q[mt];
            a = mfma16(wf[12 + mt], p2, a);
            *(u64*)(H + 2560 + c * 80 + mt * 16 + 4 * g) = qrelu_pack4(a);
        }

        // ---- output layer: hi/lo split into independent chains
        short8 p3 = *(const short8*)(H + 2560 + c * 80 + 8 * g);
        f32x4 aoh = boq;
        aoh = mfma16(wf[14], p3, aoh);
        f32x4 aol = {0.f, 0.f, 0.f, 0.f};
        aol = mfma16(wf[15], p3, aol);
        f32x4 ao = aoh + aol;

        float* orow = out + (size_t)t0 * 80 + c * 5;
        if (g == 0) {
            orow[0] = ao[0]; orow[1] = ao[1]; orow[2] = ao[2]; orow[3] = ao[3];
        } else if (g == 1) {
            orow[4] = ao[0];
        }
    }
}

extern "C" void kernel_launch(void* const* d_in, const int* in_sizes, int n_in,
                              void* d_out, int out_size, void* d_ws, size_t ws_size,
                              hipStream_t stream) {
    const float* x  = (const float*)d_in[0];
    const float* w1 = (const float*)d_in[1];
    const float* b1 = (const float*)d_in[2];
    const float* w2 = (const float*)d_in[3];
    const float* b2 = (const float*)d_in[4];
    const float* w3 = (const float*)d_in[5];
    const float* b3 = (const float*)d_in[6];
    const float* wo = (const float*)d_in[7];
    const float* bo = (const float*)d_in[8];
    float* out = (float*)d_out;

    int B = in_sizes[0] / 48;
    int ntiles = B / 16;                       // 1e6 -> 62500 exactly

    prep<<<1, 256, 0, stream>>>(w1, b1, w2, b2, w3, b3, wo, bo, (u16*)d_ws);

    int blocks = (ntiles + 3) / 4;
    if (blocks > 2048) blocks = 2048;
    mlp_mfma<<<blocks, 256, 0, stream>>>(x, (const u16*)d_ws, out, ntiles);
}

// Round 7
// 59.098 us; speedup vs baseline: 1.1656x; 1.0610x over previous
//
#include <hip/hip_runtime.h>
#include <hip/hip_bf16.h>

typedef short  short8 __attribute__((ext_vector_type(8)));
typedef float  f32x4  __attribute__((ext_vector_type(4)));
typedef unsigned int u32;
typedef unsigned long long u64;
typedef unsigned short u16;

// ---------- helpers ----------
__device__ __forceinline__ u32 f2bf(float v) {              // fp32 -> bf16 bits (RNE), prep only
    u32 u = __float_as_uint(v);
    return (u + 0x7FFFu + ((u >> 16) & 1u)) >> 16;
}
__device__ __forceinline__ float qround128(float w) {       // round(w*128) clip [-128,127]
    float q = rintf(w * 128.0f);
    return fminf(fmaxf(q, -128.0f), 127.0f);
}
// packed RNE f32x2 -> bf16x2 (v_cvt_pk_bf16_f32)
__device__ __forceinline__ u32 cvtpk(float a, float b) {
    __hip_bfloat162 h = __float22bfloat162_rn(make_float2(a, b));
    union { __hip_bfloat162 h; u32 u; } cv; cv.h = h; return cv.u;
}
__device__ __forceinline__ float q255(float v) {            // qrelu int: clamp(rndne(v),0,255)
    return fminf(fmaxf(rintf(v), 0.f), 255.f);
}
union FragU { short8 s; u32 u[4]; };
// pack two f32x4 accumulators (integer-valued after q255, exact in bf16) into a
// B-fragment: elems 0..3 = a, 4..7 = b. With the pre-permuted weight layout this
// IS the next layer's B operand — no cross-lane movement needed.
__device__ __forceinline__ short8 pack2(f32x4 a, f32x4 b) {
    FragU f;
    f.u[0] = cvtpk(q255(a[0]), q255(a[1]));
    f.u[1] = cvtpk(q255(a[2]), q255(a[3]));
    f.u[2] = cvtpk(q255(b[0]), q255(b[1]));
    f.u[3] = cvtpk(q255(b[2]), q255(b[3]));
    return f.s;
}
__device__ __forceinline__ f32x4 mfma16(short8 a, short8 b, f32x4 c) {
    return __builtin_amdgcn_mfma_f32_16x16x32_bf16(a, b, c, 0, 0, 0);
}

// ---------- ws layout ----------
// K-position permutation for L2/L3/out (so that layer-n accumulators ARE the
// layer-n+1 B-fragment): position p (lane g = (p&31)>>3, elem j = p&7) carries
// feature  f = 32*(p>>5) + 16*(j>>2) + 4*g + (j&3).
// shorts [0..8192): 16 A-frag blocks, 512 shorts, elem = blk*512 + l*8 + j,
// l: r=l&15 (out-feat), gi=l>>4.
//   blk 0..7 : L1 [mt(4)][ks(2)]  natural k = ks*32+8gi+j; val=2*q128(w1[k][mt*16+r]) (0 if k>=48)
//   blk 8..11: L2 [mt(2)][ks(2)]  f = ks*32+perm(gi,j);   val=q128(w2[f][mt*16+r])/128
//   blk 12,13: L3 [mt(2)]         f = perm(gi,j);         val=q128(w3[f][mt*16+r])/128
//   blk 14,15: Wout hi/lo         f = perm(gi,j);         val=bf16split(wout[f][r]/256) (r>=5 -> 0)
// floats @8192: [0,64) 2*q128(b1); [64,96) 2*q128(b2); [96,128) 2*q128(b3);
//   [128,144) bout zero-padded.

__global__ void prep(const float* __restrict__ w1, const float* __restrict__ b1,
                     const float* __restrict__ w2, const float* __restrict__ b2,
                     const float* __restrict__ w3, const float* __restrict__ b3,
                     const float* __restrict__ wo, const float* __restrict__ bo,
                     u16* __restrict__ wsh) {
    int t = threadIdx.x;
    for (int idx = t; idx < 16 * 512; idx += 256) {
        int blk = idx >> 9, e = idx & 511;
        int l = e >> 3, j = e & 7;
        int r  = l & 15;
        int gi = l >> 4;
        int kk = gi * 8 + j;                       // natural (L1)
        int fp = 16 * (j >> 2) + 4 * gi + (j & 3); // permuted (L2/L3/out)
        float val = 0.f;
        if (blk < 8) {
            int mt = blk >> 1, ks = blk & 1;
            int k = ks * 32 + kk, fo = mt * 16 + r;
            if (k < 48) val = 2.0f * qround128(w1[k * 64 + fo]);
        } else if (blk < 12) {
            int bi = blk - 8, mt = bi >> 1, ks = bi & 1;
            int f = ks * 32 + fp, fo = mt * 16 + r;
            val = qround128(w2[f * 32 + fo]) * (1.0f / 128.0f);
        } else if (blk < 14) {
            int mt = blk - 12;
            val = qround128(w3[fp * 32 + mt * 16 + r]) * (1.0f / 128.0f);
        } else {
            float wv = (r < 5) ? wo[fp * 5 + r] * (1.0f / 256.0f) : 0.f;
            u32 hb = f2bf(wv);
            if (blk == 14) { wsh[idx] = (u16)hb; continue; }
            val = wv - __uint_as_float(hb << 16);
        }
        wsh[idx] = (u16)f2bf(val);
    }
    float* wsf = (float*)(wsh + 8192);
    for (int i = t; i < 64; i += 256) wsf[i]       = 2.0f * qround128(b1[i]);
    for (int i = t; i < 32; i += 256) wsf[64 + i]  = 2.0f * qround128(b2[i]);
    for (int i = t; i < 32; i += 256) wsf[96 + i]  = 2.0f * qround128(b3[i]);
    for (int i = t; i < 16; i += 256) wsf[128 + i] = (i < 5) ? bo[i] : 0.f;
}

// ---------- main kernel ----------
// Fully register-resident pipeline: global load -> hi/lo split -> L1 MFMA ->
// pack2 -> L2 MFMA -> pack2 -> L3 MFMA -> pack2 -> out MFMA -> store.
// NO LDS, no cross-lane ops, no lgkmcnt anywhere (k-permuted weights make each
// layer's accumulators the next layer's B-fragment directly).

__global__ __launch_bounds__(256, 2) void mlp_mfma(const float* __restrict__ x,
                                                   const u16* __restrict__ wsh,
                                                   float* __restrict__ out, int ntiles) {
    const int tid = threadIdx.x;
    const int wid = tid >> 6, lane = tid & 63;
    const int c = lane & 15, g = lane >> 4;

    // resident weight A-fragments (64 VGPR)
    short8 wf[16];
    const short8* wv = (const short8*)wsh;
    #pragma unroll
    for (int i = 0; i < 16; ++i) wf[i] = wv[i * 64 + lane];

    // biases: acc reg r <-> out-feat mt*16 + 4g + r
    const float* wsf = (const float*)(wsh + 8192);
    f32x4 b1q[4], b2q[2], b3q[2], boq;
    #pragma unroll
    for (int i = 0; i < 4; ++i) b1q[i] = *(const f32x4*)(wsf + i * 16 + 4 * g);
    #pragma unroll
    for (int i = 0; i < 2; ++i) b2q[i] = *(const f32x4*)(wsf + 64 + i * 16 + 4 * g);
    #pragma unroll
    for (int i = 0; i < 2; ++i) b3q[i] = *(const f32x4*)(wsf + 96 + i * 16 + 4 * g);
    boq = *(const f32x4*)(wsf + 128 + 4 * g);

    const int xoff = c * 48 + g * 8;
    const int gw = blockIdx.x * 4 + wid;
    const int nw = gridDim.x * 4;
    const f32x4 zero4 = {0.f, 0.f, 0.f, 0.f};

    for (int t0 = gw; t0 < ntiles; t0 += nw) {
        // ---- x tile: lane(c,g) -> batch row c, feats 8g..8g+7 (+32.. for g<2)
        const float* xl = x + (size_t)t0 * 768 + xoff;
        float4 xa = *(const float4*)(xl);
        float4 xb = *(const float4*)(xl + 4);
        float4 xc = make_float4(0.f, 0.f, 0.f, 0.f);
        float4 xd = make_float4(0.f, 0.f, 0.f, 0.f);
        if (g < 2) { xc = *(const float4*)(xl + 32); xd = *(const float4*)(xl + 36); }

        // ---- hi/lo bf16 split (B fragments for L1)
        float v0[8] = {xa.x, xa.y, xa.z, xa.w, xb.x, xb.y, xb.z, xb.w};
        float v1[8] = {xc.x, xc.y, xc.z, xc.w, xd.x, xd.y, xd.z, xd.w};
        FragU bh0, bl0, bh1, bl1;
        #pragma unroll
        for (int p = 0; p < 4; ++p) {
            u32 uu = cvtpk(v0[2 * p], v0[2 * p + 1]);
            bh0.u[p] = uu;
            float r0 = v0[2 * p]     - __uint_as_float(uu << 16);
            float r1 = v0[2 * p + 1] - __uint_as_float(uu & 0xFFFF0000u);
            bl0.u[p] = cvtpk(r0, r1);
            u32 ww = cvtpk(v1[2 * p], v1[2 * p + 1]);
            bh1.u[p] = ww;
            float s0 = v1[2 * p]     - __uint_as_float(ww << 16);
            float s1 = v1[2 * p + 1] - __uint_as_float(ww & 0xFFFF0000u);
            bl1.u[p] = cvtpk(s0, s1);
        }

        // ---- layer 1: acc = 256*preact (4 indep mt, hi/lo indep chains)
        f32x4 acc1[4];
        #pragma unroll
        for (int mt = 0; mt < 4; ++mt) {
            f32x4 ah = mfma16(wf[mt * 2 + 0], bh0.s, b1q[mt]);
            ah = mfma16(wf[mt * 2 + 1], bh1.s, ah);
            f32x4 al = mfma16(wf[mt * 2 + 0], bl0.s, zero4);
            al = mfma16(wf[mt * 2 + 1], bl1.s, al);
            acc1[mt] = ah + al;
        }

        // ---- qrelu + repack: accumulators ARE the next B-fragments (k-permuted W)
        short8 p0 = pack2(acc1[0], acc1[1]);
        short8 p1 = pack2(acc1[2], acc1[3]);

        // ---- layer 2 (K=64): 4 independent MFMAs
        f32x4 a20 = mfma16(wf[8],  p0, b2q[0]);
        f32x4 a21 = mfma16(wf[9],  p1, zero4);
        f32x4 a22 = mfma16(wf[10], p0, b2q[1]);
        f32x4 a23 = mfma16(wf[11], p1, zero4);
        short8 p2 = pack2(a20 + a21, a22 + a23);

        // ---- layer 3 (K=32): 2 independent MFMAs
        f32x4 a30 = mfma16(wf[12], p2, b3q[0]);
        f32x4 a31 = mfma16(wf[13], p2, b3q[1]);
        short8 p3 = pack2(a30, a31);

        // ---- output: wout/256 hi + lo (indep), acc init = bout
        f32x4 aoh = mfma16(wf[14], p3, boq);
        f32x4 aol = mfma16(wf[15], p3, zero4);
        f32x4 ao = aoh + aol;

        // D: lane(c,g) reg r = logit 4g+r of batch row c; logits 0..4 exist
        float* orow = out + (size_t)t0 * 80 + c * 5;
        if (g == 0) {
            orow[0] = ao[0]; orow[1] = ao[1]; orow[2] = ao[2]; orow[3] = ao[3];
        } else if (g == 1) {
            orow[4] = ao[0];
        }
    }
}

extern "C" void kernel_launch(void* const* d_in, const int* in_sizes, int n_in,
                              void* d_out, int out_size, void* d_ws, size_t ws_size,
                              hipStream_t stream) {
    const float* x  = (const float*)d_in[0];
    const float* w1 = (const float*)d_in[1];
    const float* b1 = (const float*)d_in[2];
    const float* w2 = (const float*)d_in[3];
    const float* b2 = (const float*)d_in[4];
    const float* w3 = (const float*)d_in[5];
    const float* b3 = (const float*)d_in[6];
    const float* wo = (const float*)d_in[7];
    const float* bo = (const float*)d_in[8];
    float* out = (float*)d_out;

    int B = in_sizes[0] / 48;
    int ntiles = B / 16;                       // 1e6 -> 62500 exactly

    prep<<<1, 256, 0, stream>>>(w1, b1, w2, b2, w3, b3, wo, bo, (u16*)d_ws);

    int blocks = (ntiles + 3) / 4;
    if (blocks > 2048) blocks = 2048;
    mlp_mfma<<<blocks, 256, 0, stream>>>(x, (const u16*)d_ws, out, ntiles);
}

// Round 8
// 51.740 us; speedup vs baseline: 1.3313x; 1.1422x over previous
//
#include <hip/hip_runtime.h>
#include <hip/hip_bf16.h>

typedef short  short8 __attribute__((ext_vector_type(8)));
typedef float  f32x4  __attribute__((ext_vector_type(4)));
typedef unsigned int u32;
typedef unsigned long long u64;
typedef unsigned short u16;

// ---------- helpers ----------
__device__ __forceinline__ u32 f2bf(float v) {              // fp32 -> bf16 bits (RNE), prep only
    u32 u = __float_as_uint(v);
    return (u + 0x7FFFu + ((u >> 16) & 1u)) >> 16;
}
__device__ __forceinline__ float qround128(float w) {       // round(w*128) clip [-128,127]
    float q = rintf(w * 128.0f);
    return fminf(fmaxf(q, -128.0f), 127.0f);
}
// packed RNE f32x2 -> bf16x2 (v_cvt_pk_bf16_f32)
__device__ __forceinline__ u32 cvtpk(float a, float b) {
    __hip_bfloat162 h = __float22bfloat162_rn(make_float2(a, b));
    union { __hip_bfloat162 h; u32 u; } cv; cv.h = h; return cv.u;
}
__device__ __forceinline__ float q255(float v) {            // qrelu int: clamp(rndne(v),0,255)
    return fminf(fmaxf(rintf(v), 0.f), 255.f);
}
union FragU { short8 s; u32 u[4]; };
// pack two integer-valued f32x4 accumulators (exact in bf16) into next B-frag
__device__ __forceinline__ short8 pack2(f32x4 a, f32x4 b) {
    FragU f;
    f.u[0] = cvtpk(q255(a[0]), q255(a[1]));
    f.u[1] = cvtpk(q255(a[2]), q255(a[3]));
    f.u[2] = cvtpk(q255(b[0]), q255(b[1]));
    f.u[3] = cvtpk(q255(b[2]), q255(b[3]));
    return f.s;
}
__device__ __forceinline__ f32x4 mfma16(short8 a, short8 b, f32x4 c) {
    return __builtin_amdgcn_mfma_f32_16x16x32_bf16(a, b, c, 0, 0, 0);
}

// ---------- ws layout ----------
// L1 K-permutation (NEW, round 8): position (ks,g,j):
//   ks=0        -> feat 12g + j        (j=0..7)
//   ks=1, j<4   -> feat 12g + 8 + j
//   ks=1, g==3, j==7 -> BIAS slot (activation fixed at 1.0; weight = 2*q128(b1))
//   else        -> zero pad
// so lane g's L1 B-frag data = its own 12 contiguous x floats (uniform 3x dwordx4).
// L2/L3/out K-permutation (verified R7): position (ks,gi,j) -> f = ks*32 + 16*(j>>2) + 4*gi + (j&3).
// shorts [0..8192): 16 A-frag blocks, 512 shorts, elem = blk*512 + l*8 + j, l: r=l&15, gi=l>>4.
//   blk 0..7 : L1 [mt(4)][ks(2)]  val = 2*q128(w1[f][mt*16+r]) per mapping above
//   blk 8..11: L2 [mt(2)][ks(2)]  val = q128(w2[f][mt*16+r])/128
//   blk 12,13: L3 [mt(2)]         val = q128(w3[f][mt*16+r])/128
//   blk 14,15: Wout hi/lo         val = bf16split(wout[f][r]/256) (r>=5 -> 0)
// floats @short-offset 8192: [64,96) 2*q128(b2); [96,128) 2*q128(b3); [128,144) bout (padded).

__global__ void prep(const float* __restrict__ w1, const float* __restrict__ b1,
                     const float* __restrict__ w2, const float* __restrict__ b2,
                     const float* __restrict__ w3, const float* __restrict__ b3,
                     const float* __restrict__ wo, const float* __restrict__ bo,
                     u16* __restrict__ wsh) {
    int idx = blockIdx.x * 256 + threadIdx.x;      // 32 blocks x 256 = 8192 = 16*512
    if (idx < 16 * 512) {
        int blk = idx >> 9, e = idx & 511;
        int l = e >> 3, j = e & 7;
        int r  = l & 15;
        int gi = l >> 4;
        int fp = 16 * (j >> 2) + 4 * gi + (j & 3); // permuted (L2/L3/out)
        float val = 0.f;
        if (blk < 8) {
            int mt = blk >> 1, ks = blk & 1;
            int fo = mt * 16 + r;
            if (ks == 0) {
                val = 2.0f * qround128(w1[(12 * gi + j) * 64 + fo]);
            } else if (j < 4) {
                val = 2.0f * qround128(w1[(12 * gi + 8 + j) * 64 + fo]);
            } else if (gi == 3 && j == 7) {
                val = 2.0f * qround128(b1[fo]);    // bias slot (activation = 1.0)
            }
        } else if (blk < 12) {
            int bi = blk - 8, mt = bi >> 1, ks = bi & 1;
            int f = ks * 32 + fp, fo = mt * 16 + r;
            val = qround128(w2[f * 32 + fo]) * (1.0f / 128.0f);
        } else if (blk < 14) {
            int mt = blk - 12;
            val = qround128(w3[fp * 32 + mt * 16 + r]) * (1.0f / 128.0f);
        } else {
            float wv = (r < 5) ? wo[fp * 5 + r] * (1.0f / 256.0f) : 0.f;
            u32 hb = f2bf(wv);
            if (blk == 14) { wsh[idx] = (u16)hb; return; }
            val = wv - __uint_as_float(hb << 16);
        }
        wsh[idx] = (u16)f2bf(val);
    }
    if (blockIdx.x == 0) {
        int t = threadIdx.x;
        float* wsf = (float*)(wsh + 8192);
        for (int i = t; i < 32; i += 256) wsf[64 + i]  = 2.0f * qround128(b2[i]);
        for (int i = t; i < 32; i += 256) wsf[96 + i]  = 2.0f * qround128(b3[i]);
        for (int i = t; i < 16; i += 256) wsf[128 + i] = (i < 5) ? bo[i] : 0.f;
    }
}

// ---------- main kernel ----------
// Register-resident pipeline (R7-verified dataflow), now 4 tiles (64 rows) per
// wave iteration: all 12 x-loads issued up front so tiles 1-3's HBM latency
// hides under tiles 0-2's compute; one serial chain amortizes 4x the payload.
// No LDS, no cross-lane ops anywhere.

__global__ __launch_bounds__(256, 2) void mlp_mfma(const float* __restrict__ x,
                                                   const u16* __restrict__ wsh,
                                                   float* __restrict__ out, int ntiles) {
    const int tid = threadIdx.x;
    const int wid = tid >> 6, lane = tid & 63;
    const int c = lane & 15, g = lane >> 4;

    // resident weight A-fragments (64 VGPR)
    short8 wf[16];
    const short8* wv = (const short8*)wsh;
    #pragma unroll
    for (int i = 0; i < 16; ++i) wf[i] = wv[i * 64 + lane];

    // biases (b1 folded into L1 K-slot): acc reg r <-> out-feat mt*16 + 4g + r
    const float* wsf = (const float*)(wsh + 8192);
    f32x4 b2q[2], b3q[2], boq;
    #pragma unroll
    for (int i = 0; i < 2; ++i) b2q[i] = *(const f32x4*)(wsf + 64 + i * 16 + 4 * g);
    #pragma unroll
    for (int i = 0; i < 2; ++i) b3q[i] = *(const f32x4*)(wsf + 96 + i * 16 + 4 * g);
    boq = *(const f32x4*)(wsf + 128 + 4 * g);

    const int xoff = c * 48 + g * 12;              // lane owns feats 12g..12g+11 of row c
    const int npacks = (ntiles + 3) >> 2;
    const int gw = blockIdx.x * 4 + wid;
    const int nw = gridDim.x * 4;
    const f32x4 zero4 = {0.f, 0.f, 0.f, 0.f};

    for (int p = gw; p < npacks; p += nw) {
        // ---- issue ALL 4 tiles' loads first (3 uniform dwordx4 per lane per tile)
        float4 xq0[4], xq1[4], xq2[4];
        #pragma unroll
        for (int i = 0; i < 4; ++i) {
            int t = 4 * p + i;
            int tl = (t < ntiles) ? t : (ntiles - 1);
            const float* xl = x + (size_t)tl * 768 + xoff;
            xq0[i] = *(const float4*)(xl);
            xq1[i] = *(const float4*)(xl + 4);
            xq2[i] = *(const float4*)(xl + 8);
        }

        // ---- per-tile register pipeline
        #pragma unroll
        for (int i = 0; i < 4; ++i) {
            float v[12] = {xq0[i].x, xq0[i].y, xq0[i].z, xq0[i].w,
                           xq1[i].x, xq1[i].y, xq1[i].z, xq1[i].w,
                           xq2[i].x, xq2[i].y, xq2[i].z, xq2[i].w};
            // hi/lo bf16 split: 12 real values
            FragU bh0, bl0, bh1, bl1;
            #pragma unroll
            for (int q = 0; q < 4; ++q) {
                u32 uu = cvtpk(v[2 * q], v[2 * q + 1]);
                bh0.u[q] = uu;
                float r0 = v[2 * q]     - __uint_as_float(uu << 16);
                float r1 = v[2 * q + 1] - __uint_as_float(uu & 0xFFFF0000u);
                bl0.u[q] = cvtpk(r0, r1);
            }
            #pragma unroll
            for (int q = 0; q < 2; ++q) {
                u32 uu = cvtpk(v[8 + 2 * q], v[9 + 2 * q]);
                bh1.u[q] = uu;
                float r0 = v[8 + 2 * q] - __uint_as_float(uu << 16);
                float r1 = v[9 + 2 * q] - __uint_as_float(uu & 0xFFFF0000u);
                bl1.u[q] = cvtpk(r0, r1);
            }
            bh1.u[2] = 0u;
            bh1.u[3] = (g == 3) ? 0x3F800000u : 0u;   // bias-slot activation 1.0 (elem 7)
            bl1.u[2] = 0u; bl1.u[3] = 0u;

            // layer 1: acc = 256*preact (bias enters via k=63 slot)
            f32x4 acc1[4];
            #pragma unroll
            for (int mt = 0; mt < 4; ++mt) {
                f32x4 ah = mfma16(wf[mt * 2 + 0], bh0.s, zero4);
                ah = mfma16(wf[mt * 2 + 1], bh1.s, ah);
                f32x4 al = mfma16(wf[mt * 2 + 0], bl0.s, zero4);
                al = mfma16(wf[mt * 2 + 1], bl1.s, al);
                acc1[mt] = ah + al;
            }
            short8 p0 = pack2(acc1[0], acc1[1]);
            short8 p1 = pack2(acc1[2], acc1[3]);

            // layer 2 (K=64)
            f32x4 a20 = mfma16(wf[8],  p0, b2q[0]);
            f32x4 a21 = mfma16(wf[9],  p1, zero4);
            f32x4 a22 = mfma16(wf[10], p0, b2q[1]);
            f32x4 a23 = mfma16(wf[11], p1, zero4);
            short8 p2 = pack2(a20 + a21, a22 + a23);

            // layer 3 (K=32)
            f32x4 a30 = mfma16(wf[12], p2, b3q[0]);
            f32x4 a31 = mfma16(wf[13], p2, b3q[1]);
            short8 p3 = pack2(a30, a31);

            // output: wout/256 hi + lo, acc init = bout
            f32x4 aoh = mfma16(wf[14], p3, boq);
            f32x4 aol = mfma16(wf[15], p3, zero4);
            f32x4 ao = aoh + aol;

            int t = 4 * p + i;
            if (t < ntiles) {
                float* orow = out + (size_t)t * 80 + c * 5;
                if (g == 0) {
                    orow[0] = ao[0]; orow[1] = ao[1]; orow[2] = ao[2]; orow[3] = ao[3];
                } else if (g == 1) {
                    orow[4] = ao[0];
                }
            }
        }
    }
}

extern "C" void kernel_launch(void* const* d_in, const int* in_sizes, int n_in,
                              void* d_out, int out_size, void* d_ws, size_t ws_size,
                              hipStream_t stream) {
    const float* x  = (const float*)d_in[0];
    const float* w1 = (const float*)d_in[1];
    const float* b1 = (const float*)d_in[2];
    const float* w2 = (const float*)d_in[3];
    const float* b2 = (const float*)d_in[4];
    const float* w3 = (const float*)d_in[5];
    const float* b3 = (const float*)d_in[6];
    const float* wo = (const float*)d_in[7];
    const float* bo = (const float*)d_in[8];
    float* out = (float*)d_out;

    int B = in_sizes[0] / 48;
    int ntiles = B / 16;                       // 1e6 -> 62500
    int npacks = (ntiles + 3) / 4;             // -> 15625

    prep<<<32, 256, 0, stream>>>(w1, b1, w2, b2, w3, b3, wo, bo, (u16*)d_ws);

    int blocks = (npacks + 7) / 8;             // ~2 packs per wave
    if (blocks > 2048) blocks = 2048;
    mlp_mfma<<<blocks, 256, 0, stream>>>(x, (const u16*)d_ws, out, ntiles);
}

// Round 9
// 51.373 us; speedup vs baseline: 1.3408x; 1.0071x over previous
//
#include <hip/hip_runtime.h>
#include <hip/hip_bf16.h>

typedef short  short8 __attribute__((ext_vector_type(8)));
typedef float  f32x4  __attribute__((ext_vector_type(4)));
typedef unsigned int u32;
typedef unsigned long long u64;
typedef unsigned short u16;

// ---------- helpers ----------
__device__ __forceinline__ u32 f2bf(float v) {              // fp32 -> bf16 bits (RNE), prep only
    u32 u = __float_as_uint(v);
    return (u + 0x7FFFu + ((u >> 16) & 1u)) >> 16;
}
__device__ __forceinline__ float qround128(float w) {       // round(w*128) clip [-128,127]
    float q = rintf(w * 128.0f);
    return fminf(fmaxf(q, -128.0f), 127.0f);
}
__device__ __forceinline__ u32 cvtpk(float a, float b) {    // v_cvt_pk_bf16_f32
    __hip_bfloat162 h = __float22bfloat162_rn(make_float2(a, b));
    union { __hip_bfloat162 h; u32 u; } cv; cv.h = h; return cv.u;
}
__device__ __forceinline__ float q255(float v) {            // qrelu int: clamp(rndne(v),0,255)
    return fminf(fmaxf(rintf(v), 0.f), 255.f);
}
union FragU { short8 s; u32 u[4]; };
__device__ __forceinline__ short8 pack2(f32x4 a, f32x4 b) {
    FragU f;
    f.u[0] = cvtpk(q255(a[0]), q255(a[1]));
    f.u[1] = cvtpk(q255(a[2]), q255(a[3]));
    f.u[2] = cvtpk(q255(b[0]), q255(b[1]));
    f.u[3] = cvtpk(q255(b[2]), q255(b[3]));
    return f.s;
}
__device__ __forceinline__ f32x4 mfma16(short8 a, short8 b, f32x4 c) {
    return __builtin_amdgcn_mfma_f32_16x16x32_bf16(a, b, c, 0, 0, 0);
}
// async global->LDS, 16B per lane: LDS dest is wave-uniform base + lane*16,
// global src is per-lane. (learn_hip m97/m104 semantics)
__device__ __forceinline__ void gload16(const float* src, float* lds_dst) {
    __builtin_amdgcn_global_load_lds(
        (const __attribute__((address_space(1))) u32*)src,
        (__attribute__((address_space(3))) u32*)lds_dst,
        16, 0, 0);
}

// ---------- ws layout (byte-identical to verified round 8) ----------
__global__ void prep(const float* __restrict__ w1, const float* __restrict__ b1,
                     const float* __restrict__ w2, const float* __restrict__ b2,
                     const float* __restrict__ w3, const float* __restrict__ b3,
                     const float* __restrict__ wo, const float* __restrict__ bo,
                     u16* __restrict__ wsh) {
    int idx = blockIdx.x * 256 + threadIdx.x;      // 32 blocks x 256 = 8192 = 16*512
    if (idx < 16 * 512) {
        int blk = idx >> 9, e = idx & 511;
        int l = e >> 3, j = e & 7;
        int r  = l & 15;
        int gi = l >> 4;
        int fp = 16 * (j >> 2) + 4 * gi + (j & 3); // permuted (L2/L3/out)
        float val = 0.f;
        if (blk < 8) {
            int mt = blk >> 1, ks = blk & 1;
            int fo = mt * 16 + r;
            if (ks == 0) {
                val = 2.0f * qround128(w1[(12 * gi + j) * 64 + fo]);
            } else if (j < 4) {
                val = 2.0f * qround128(w1[(12 * gi + 8 + j) * 64 + fo]);
            } else if (gi == 3 && j == 7) {
                val = 2.0f * qround128(b1[fo]);    // bias slot (activation = 1.0)
            }
        } else if (blk < 12) {
            int bi = blk - 8, mt = bi >> 1, ks = bi & 1;
            int f = ks * 32 + fp, fo = mt * 16 + r;
            val = qround128(w2[f * 32 + fo]) * (1.0f / 128.0f);
        } else if (blk < 14) {
            int mt = blk - 12;
            val = qround128(w3[fp * 32 + mt * 16 + r]) * (1.0f / 128.0f);
        } else {
            float wv = (r < 5) ? wo[fp * 5 + r] * (1.0f / 256.0f) : 0.f;
            u32 hb = f2bf(wv);
            if (blk == 14) { wsh[idx] = (u16)hb; return; }
            val = wv - __uint_as_float(hb << 16);
        }
        wsh[idx] = (u16)f2bf(val);
    }
    if (blockIdx.x == 0) {
        int t = threadIdx.x;
        float* wsf = (float*)(wsh + 8192);
        for (int i = t; i < 32; i += 256) wsf[64 + i]  = 2.0f * qround128(b2[i]);
        for (int i = t; i < 32; i += 256) wsf[96 + i]  = 2.0f * qround128(b3[i]);
        for (int i = t; i < 16; i += 256) wsf[128 + i] = (i < 5) ? bo[i] : 0.f;
    }
}

// ---------- main kernel ----------
// R8-verified register pipeline + wave-private LDS double-buffered staging via
// global_load_lds with COUNTED vmcnt(6): next pack's 6 DMA loads stay in flight
// across the whole compute phase; payload uses zero VGPRs -> 3 waves/SIMD.
// No barriers (wave-private slabs), no cross-lane ops.

__global__ __launch_bounds__(256, 3) void mlp_mfma(const float* __restrict__ x,
                                                   const u16* __restrict__ wsh,
                                                   float* __restrict__ out, int ntiles) {
    // [wave][buf][2 tiles x 768 floats] = 4*2*1536*4B = 49152 B
    __shared__ __align__(16) float smem[4][2][1536];
    const int tid = threadIdx.x;
    const int wid = tid >> 6, lane = tid & 63;
    const int c = lane & 15, g = lane >> 4;

    // resident weight A-fragments (64 VGPR)
    short8 wf[16];
    const short8* wv = (const short8*)wsh;
    #pragma unroll
    for (int i = 0; i < 16; ++i) wf[i] = wv[i * 64 + lane];

    // biases (b1 folded into L1 K-slot)
    const float* wsf = (const float*)(wsh + 8192);
    f32x4 b2q[2], b3q[2], boq;
    #pragma unroll
    for (int i = 0; i < 2; ++i) b2q[i] = *(const f32x4*)(wsf + 64 + i * 16 + 4 * g);
    #pragma unroll
    for (int i = 0; i < 2; ++i) b3q[i] = *(const f32x4*)(wsf + 96 + i * 16 + 4 * g);
    boq = *(const f32x4*)(wsf + 128 + 4 * g);

    const int npacks = (ntiles + 1) >> 1;
    const int gw = blockIdx.x * 4 + wid;
    const int nw = gridDim.x * 4;
    const f32x4 zero4 = {0.f, 0.f, 0.f, 0.f};
    const int roff = c * 48 + g * 12;              // lane's floats within a tile

    // stage one pack (2 consecutive tiles = 6144B contiguous) into buf
    auto stage = [&](int buf, int pk) {
        #pragma unroll
        for (int s = 0; s < 6; ++s) {
            int tt = 2 * pk + (s >= 3 ? 1 : 0);
            if (tt >= ntiles) tt = ntiles - 1;     // clamp (uniform)
            const float* src = x + (size_t)tt * 768 + (s % 3) * 256 + lane * 4;
            gload16(src, &smem[wid][buf][s * 256]);
        }
    };

    int p = gw;
    int buf = 0;
    if (p < npacks) stage(0, p);

    for (; p < npacks; p += nw) {
        const int pn = p + nw;
        const bool have = pn < npacks;
        if (have) {
            stage(buf ^ 1, pn);
            asm volatile("s_waitcnt vmcnt(6)" ::: "memory");   // prev 6 DMA done; new 6 in flight
        } else {
            asm volatile("s_waitcnt vmcnt(0)" ::: "memory");
        }
        __builtin_amdgcn_sched_barrier(0);

        #pragma unroll
        for (int i = 0; i < 2; ++i) {
            const float* T = &smem[wid][buf][i * 768];
            float4 q0 = *(const float4*)(T + roff);
            float4 q1 = *(const float4*)(T + roff + 4);
            float4 q2 = *(const float4*)(T + roff + 8);
            float v[12] = {q0.x, q0.y, q0.z, q0.w,
                           q1.x, q1.y, q1.z, q1.w,
                           q2.x, q2.y, q2.z, q2.w};

            // hi/lo bf16 split
            FragU bh0, bl0, bh1, bl1;
            #pragma unroll
            for (int q = 0; q < 4; ++q) {
                u32 uu = cvtpk(v[2 * q], v[2 * q + 1]);
                bh0.u[q] = uu;
                float r0 = v[2 * q]     - __uint_as_float(uu << 16);
                float r1 = v[2 * q + 1] - __uint_as_float(uu & 0xFFFF0000u);
                bl0.u[q] = cvtpk(r0, r1);
            }
            #pragma unroll
            for (int q = 0; q < 2; ++q) {
                u32 uu = cvtpk(v[8 + 2 * q], v[9 + 2 * q]);
                bh1.u[q] = uu;
                float r0 = v[8 + 2 * q] - __uint_as_float(uu << 16);
                float r1 = v[9 + 2 * q] - __uint_as_float(uu & 0xFFFF0000u);
                bl1.u[q] = cvtpk(r0, r1);
            }
            bh1.u[2] = 0u;
            bh1.u[3] = (g == 3) ? 0x3F800000u : 0u;   // bias-slot activation 1.0
            bl1.u[2] = 0u; bl1.u[3] = 0u;

            // layer 1: acc = 256*preact (bias via k=63 slot)
            f32x4 acc1[4];
            #pragma unroll
            for (int mt = 0; mt < 4; ++mt) {
                f32x4 ah = mfma16(wf[mt * 2 + 0], bh0.s, zero4);
                ah = mfma16(wf[mt * 2 + 1], bh1.s, ah);
                f32x4 al = mfma16(wf[mt * 2 + 0], bl0.s, zero4);
                al = mfma16(wf[mt * 2 + 1], bl1.s, al);
                acc1[mt] = ah + al;
            }
            short8 p0 = pack2(acc1[0], acc1[1]);
            short8 p1 = pack2(acc1[2], acc1[3]);

            // layer 2 (K=64)
            f32x4 a20 = mfma16(wf[8],  p0, b2q[0]);
            f32x4 a21 = mfma16(wf[9],  p1, zero4);
            f32x4 a22 = mfma16(wf[10], p0, b2q[1]);
            f32x4 a23 = mfma16(wf[11], p1, zero4);
            short8 p2 = pack2(a20 + a21, a22 + a23);

            // layer 3 (K=32)
            f32x4 a30 = mfma16(wf[12], p2, b3q[0]);
            f32x4 a31 = mfma16(wf[13], p2, b3q[1]);
            short8 p3 = pack2(a30, a31);

            // output: wout/256 hi + lo, acc init = bout
            f32x4 aoh = mfma16(wf[14], p3, boq);
            f32x4 aol = mfma16(wf[15], p3, zero4);
            f32x4 ao = aoh + aol;

            int t = 2 * p + i;
            if (t < ntiles) {
                float* orow = out + (size_t)t * 80 + c * 5;
                if (g == 0) {
                    *(float4*)orow = make_float4(ao[0], ao[1], ao[2], ao[3]);
                } else if (g == 1) {
                    orow[4] = ao[0];
                }
            }
        }
        buf ^= 1;
    }
}

extern "C" void kernel_launch(void* const* d_in, const int* in_sizes, int n_in,
                              void* d_out, int out_size, void* d_ws, size_t ws_size,
                              hipStream_t stream) {
    const float* x  = (const float*)d_in[0];
    const float* w1 = (const float*)d_in[1];
    const float* b1 = (const float*)d_in[2];
    const float* w2 = (const float*)d_in[3];
    const float* b2 = (const float*)d_in[4];
    const float* w3 = (const float*)d_in[5];
    const float* b3 = (const float*)d_in[6];
    const float* wo = (const float*)d_in[7];
    const float* bo = (const float*)d_in[8];
    float* out = (float*)d_out;

    int B = in_sizes[0] / 48;
    int ntiles = B / 16;                       // 1e6 -> 62500
    int npacks = (ntiles + 1) / 2;             // -> 31250

    prep<<<32, 256, 0, stream>>>(w1, b1, w2, b2, w3, b3, wo, bo, (u16*)d_ws);

    int blocks = (npacks + 3) / 4;
    if (blocks > 2048) blocks = 2048;
    mlp_mfma<<<blocks, 256, 0, stream>>>(x, (const u16*)d_ws, out, ntiles);
}